// Round 1
// baseline (1484.108 us; speedup 1.0000x reference)
//
#include <hip/hip_runtime.h>
#include <stdint.h>

#define IN_DIM 1024
#define H_DIM  1024
#define BATCH  8192
#define KDIM   2048   // IN + H
#define NDIM   4096   // 4*H
#define BM     128
#define BN     128
#define BK     32

typedef __bf16 bf16x8 __attribute__((ext_vector_type(8)));
typedef float  f32x4  __attribute__((ext_vector_type(4)));
typedef unsigned int u32;

static __device__ __forceinline__ unsigned short f2bf(float f) {
  u32 u = __builtin_bit_cast(u32, f);
  u += 0x7FFFu + ((u >> 16) & 1u);   // round-to-nearest-even
  return (unsigned short)(u >> 16);
}

static __device__ __forceinline__ float sigm(float x) {
  return 1.0f / (1.0f + __expf(-x));
}
static __device__ __forceinline__ float tanh_fast(float x) {
  float e = __expf(-2.0f * fabsf(x));     // in (0,1], no overflow
  float t = (1.0f - e) / (1.0f + e);
  return copysignf(t, x);
}

// ---------------- prep 1: A = [x | h] -> bf16 [BATCH][KDIM] ----------------
__global__ void conv_a(const float* __restrict__ x, const float* __restrict__ h,
                       unsigned short* __restrict__ A) {
  const int total = BATCH * KDIM / 4;
  for (int i = blockIdx.x * blockDim.x + threadIdx.x; i < total;
       i += gridDim.x * blockDim.x) {
    int b = i >> 9;              // 512 quads per row
    int k = (i & 511) << 2;
    const float* src = (k < IN_DIM) ? (x + (size_t)b * IN_DIM + k)
                                    : (h + (size_t)b * H_DIM + (k - IN_DIM));
    float4 v = *reinterpret_cast<const float4*>(src);
    ushort4 o;
    o.x = f2bf(v.x); o.y = f2bf(v.y); o.z = f2bf(v.z); o.w = f2bf(v.w);
    *reinterpret_cast<ushort4*>(A + (size_t)b * KDIM + k) = o;
  }
}

// ---- prep 2: Bt[j][k] = W[k][c(j)], bf16, gate-interleaved cols j=4u+g ----
__global__ void conv_b(const float* __restrict__ Wi, const float* __restrict__ Wh,
                       unsigned short* __restrict__ Bt) {
  __shared__ float tile[32][33];
  int k0 = blockIdx.x * 32;            // 0..2047 (k of combined [Wi;Wh])
  int c0 = blockIdx.y * 32;            // 0..4095 (orig col)
  int tx = threadIdx.x;                // 0..31
  int ty = threadIdx.y;                // 0..7
  const float* src = (k0 < IN_DIM) ? (Wi + (size_t)k0 * NDIM)
                                   : (Wh + (size_t)(k0 - IN_DIM) * NDIM);
  for (int i = 0; i < 4; i++) {
    int r = ty + 8 * i;
    tile[r][tx] = src[(size_t)r * NDIM + c0 + tx];
  }
  __syncthreads();
  int g = c0 >> 10;                    // gate index (tile doesn't straddle)
  int ubase = c0 & 1023;
  for (int i = 0; i < 4; i++) {
    int cc = ty + 8 * i;
    int j = 4 * (ubase + cc) + g;      // interleaved output row
    Bt[(size_t)j * KDIM + k0 + tx] = f2bf(tile[tx][cc]);
  }
}

// ---------------- prep 3: bias[j] = bi[c(j)] + bh[c(j)] ----------------
__global__ void conv_bias(const float* __restrict__ bi, const float* __restrict__ bh,
                          float* __restrict__ bias) {
  int j = blockIdx.x * blockDim.x + threadIdx.x;
  if (j < NDIM) {
    int c = ((j & 3) << 10) + (j >> 2);
    bias[j] = bi[c] + bh[c];
  }
}

// ---------------- GEMM + fused LSTM epilogue ----------------
static __device__ __forceinline__ void gload_lds16(const void* g, void* l) {
  __builtin_amdgcn_global_load_lds(
      (const __attribute__((address_space(1))) u32*)g,
      (__attribute__((address_space(3))) u32*)l, 16, 0, 0);
}

__launch_bounds__(256)
__global__ void lstm_gemm(const unsigned short* __restrict__ A,
                          const unsigned short* __restrict__ Bt,
                          const float* __restrict__ bias,
                          const float* __restrict__ Cin,
                          float* __restrict__ Hout,
                          float* __restrict__ Cout) {
  __shared__ __align__(16) char smem[16384];   // As 8K | Bs 8K ; epilogue Gs 16K

  int t = threadIdx.x;
  int l = t & 63;
  int wave = t >> 6;
  int lane16 = l & 15;
  int kg = l >> 4;
  int wr = wave >> 1, wc = wave & 1;

  int bid = blockIdx.x;                 // 2048 blocks
  int swz = (bid & 7) * 256 + (bid >> 3);   // bijective XCD swizzle (2048%8==0)
  int tile_m = swz >> 5;                // 64 M-tiles
  int tile_n = swz & 31;                // 32 N-tiles
  int brow = tile_m * BM;
  int bcol = tile_n * BN;

  // staging: thread t loads 16B; rows (t>>2) and (t>>2)+64; LDS linear = t*16
  int srow = t >> 2;
  int sseg = (t & 3) * 8;
  const unsigned short* ga0 = A  + (size_t)(brow + srow)      * KDIM + sseg;
  const unsigned short* ga1 = A  + (size_t)(brow + srow + 64) * KDIM + sseg;
  const unsigned short* gb0 = Bt + (size_t)(bcol + srow)      * KDIM + sseg;
  const unsigned short* gb1 = Bt + (size_t)(bcol + srow + 64) * KDIM + sseg;
  char* lA0 = smem         + t * 16;
  char* lA1 = smem + 4096  + t * 16;
  char* lB0 = smem + 8192  + t * 16;
  char* lB1 = smem + 12288 + t * 16;

  f32x4 acc[4][4];
#pragma unroll
  for (int m = 0; m < 4; m++)
#pragma unroll
    for (int n = 0; n < 4; n++) acc[m][n] = (f32x4){0.f, 0.f, 0.f, 0.f};

  // fragment LDS byte offsets (row-major [128][32] bf16 = 64B rows)
  int aoff[4], boff[4];
#pragma unroll
  for (int m = 0; m < 4; m++)
    aoff[m] = (wr * 64 + m * 16 + lane16) * 64 + kg * 16;
#pragma unroll
  for (int n = 0; n < 4; n++)
    boff[n] = 8192 + (wc * 64 + n * 16 + lane16) * 64 + kg * 16;

  for (int kt = 0; kt < KDIM; kt += BK) {
    gload_lds16(ga0 + kt, lA0);
    gload_lds16(ga1 + kt, lA1);
    gload_lds16(gb0 + kt, lB0);
    gload_lds16(gb1 + kt, lB1);
    __syncthreads();
    bf16x8 af[4], bfr[4];
#pragma unroll
    for (int n = 0; n < 4; n++)
      bfr[n] = *reinterpret_cast<const bf16x8*>(smem + boff[n]);
#pragma unroll
    for (int m = 0; m < 4; m++)
      af[m] = *reinterpret_cast<const bf16x8*>(smem + aoff[m]);
#pragma unroll
    for (int m = 0; m < 4; m++)
#pragma unroll
      for (int n = 0; n < 4; n++)
        acc[m][n] = __builtin_amdgcn_mfma_f32_16x16x32_bf16(af[m], bfr[n],
                                                            acc[m][n], 0, 0, 0);
    __syncthreads();
  }

  // bias (function of column only)
  float bv[4];
#pragma unroll
  for (int n = 0; n < 4; n++)
    bv[n] = bias[bcol + wc * 64 + n * 16 + lane16];

  float* Gs = reinterpret_cast<float*>(smem);   // [32][128] per m-chunk

#pragma unroll 1
  for (int m = 0; m < 4; m++) {
    if (m) __syncthreads();
    // C/D layout: col = lane&15, row = (lane>>4)*4 + reg  [verified m89/m91]
#pragma unroll
    for (int n = 0; n < 4; n++)
#pragma unroll
      for (int r = 0; r < 4; r++)
        Gs[(wr * 16 + kg * 4 + r) * 128 + wc * 64 + n * 16 + lane16] =
            acc[m][n][r] + bv[n];
    __syncthreads();
#pragma unroll
    for (int q = 0; q < 4; q++) {
      int item = t + q * 256;            // 32 rows x 32 units
      int s = item >> 5;
      int u = item & 31;
      float4 g4 = *reinterpret_cast<const float4*>(&Gs[s * 128 + u * 4]);
      int grow = brow + (s >> 4) * 64 + m * 16 + (s & 15);
      int gu = (bcol >> 2) + u;
      float Ig = sigm(g4.x);
      float Fg = sigm(g4.y);
      float Gg = tanh_fast(g4.z);
      float Og = sigm(g4.w);
      size_t idx = (size_t)grow * H_DIM + gu;
      float cv = Cin[idx];
      float cn = Fg * cv + Ig * Gg;
      float hn = Og * tanh_fast(cn);
      Hout[idx] = hn;
      Cout[idx] = cn;
    }
  }
}

extern "C" void kernel_launch(void* const* d_in, const int* in_sizes, int n_in,
                              void* d_out, int out_size, void* d_ws, size_t ws_size,
                              hipStream_t stream) {
  const float* x  = (const float*)d_in[0];
  const float* h  = (const float*)d_in[1];
  const float* c  = (const float*)d_in[2];
  const float* Wi = (const float*)d_in[3];
  const float* bi = (const float*)d_in[4];
  const float* Wh = (const float*)d_in[5];
  const float* bh = (const float*)d_in[6];

  float* out  = (float*)d_out;
  float* Hout = out;
  float* Cout = out + (size_t)BATCH * H_DIM;

  // workspace layout: A bf16 (32 MiB) | Bt bf16 (16 MiB) | bias f32 (16 KiB)
  unsigned short* Abf = (unsigned short*)d_ws;
  unsigned short* Btb = (unsigned short*)((char*)d_ws + 33554432);
  float*          bsf = (float*)((char*)d_ws + 50331648);

  conv_a<<<2048, 256, 0, stream>>>(x, h, Abf);
  conv_b<<<dim3(64, 128), dim3(32, 8), 0, stream>>>(Wi, Wh, Btb);
  conv_bias<<<16, 256, 0, stream>>>(bi, bh, bsf);
  lstm_gemm<<<2048, 256, 0, stream>>>(Abf, Btb, bsf, c, Hout, Cout);
}

// Round 2
// 229.212 us; speedup vs baseline: 6.4748x; 6.4748x over previous
//
#include <hip/hip_runtime.h>
#include <stdint.h>

#define IN_DIM 1024
#define H_DIM  1024
#define BATCH  8192
#define KDIM   2048   // IN + H
#define NDIM   4096   // 4*H
#define BM     128
#define BN     128
#define BK     32

typedef __bf16 bf16x8 __attribute__((ext_vector_type(8)));
typedef float  f32x4  __attribute__((ext_vector_type(4)));
typedef unsigned int u32;

static __device__ __forceinline__ unsigned short f2bf(float f) {
  u32 u = __builtin_bit_cast(u32, f);
  u += 0x7FFFu + ((u >> 16) & 1u);   // round-to-nearest-even
  return (unsigned short)(u >> 16);
}

static __device__ __forceinline__ float sigm(float x) {
  return 1.0f / (1.0f + __expf(-x));
}
static __device__ __forceinline__ float tanh_fast(float x) {
  float e = __expf(-2.0f * fabsf(x));     // in (0,1], no overflow
  float t = (1.0f - e) / (1.0f + e);
  return copysignf(t, x);
}

// ---------------- prep 1: A = [x | h] -> bf16 [BATCH][KDIM] ----------------
__global__ void conv_a(const float* __restrict__ x, const float* __restrict__ h,
                       unsigned short* __restrict__ A) {
  const int total = BATCH * KDIM / 4;
  for (int i = blockIdx.x * blockDim.x + threadIdx.x; i < total;
       i += gridDim.x * blockDim.x) {
    int b = i >> 9;              // 512 quads per row
    int k = (i & 511) << 2;
    const float* src = (k < IN_DIM) ? (x + (size_t)b * IN_DIM + k)
                                    : (h + (size_t)b * H_DIM + (k - IN_DIM));
    float4 v = *reinterpret_cast<const float4*>(src);
    ushort4 o;
    o.x = f2bf(v.x); o.y = f2bf(v.y); o.z = f2bf(v.z); o.w = f2bf(v.w);
    *reinterpret_cast<ushort4*>(A + (size_t)b * KDIM + k) = o;
  }
}

// ---- prep 2: Bt[j][k] = W[k][c(j)], bf16, gate-interleaved cols j=4u+g ----
__global__ void conv_b(const float* __restrict__ Wi, const float* __restrict__ Wh,
                       unsigned short* __restrict__ Bt) {
  __shared__ float tile[32][33];
  int k0 = blockIdx.x * 32;            // 0..2047 (k of combined [Wi;Wh])
  int c0 = blockIdx.y * 32;            // 0..4095 (orig col)
  int tx = threadIdx.x;                // 0..31
  int ty = threadIdx.y;                // 0..7
  const float* src = (k0 < IN_DIM) ? (Wi + (size_t)k0 * NDIM)
                                   : (Wh + (size_t)(k0 - IN_DIM) * NDIM);
  for (int i = 0; i < 4; i++) {
    int r = ty + 8 * i;
    tile[r][tx] = src[(size_t)r * NDIM + c0 + tx];
  }
  __syncthreads();
  int g = c0 >> 10;                    // gate index (tile doesn't straddle)
  int ubase = c0 & 1023;
  for (int i = 0; i < 4; i++) {
    int cc = ty + 8 * i;
    int j = 4 * (ubase + cc) + g;      // interleaved output row
    Bt[(size_t)j * KDIM + k0 + tx] = f2bf(tile[tx][cc]);
  }
}

// ---------------- prep 3: bias[j] = bi[c(j)] + bh[c(j)] ----------------
__global__ void conv_bias(const float* __restrict__ bi, const float* __restrict__ bh,
                          float* __restrict__ bias) {
  int j = blockIdx.x * blockDim.x + threadIdx.x;
  if (j < NDIM) {
    int c = ((j & 3) << 10) + (j >> 2);
    bias[j] = bi[c] + bh[c];
  }
}

// ---------------- GEMM + fused LSTM epilogue ----------------
static __device__ __forceinline__ void gload_lds16(const void* g, void* l) {
  __builtin_amdgcn_global_load_lds(
      (const __attribute__((address_space(1))) u32*)g,
      (__attribute__((address_space(3))) u32*)l, 16, 0, 0);
}

__launch_bounds__(256)
__global__ void lstm_gemm(const unsigned short* __restrict__ A,
                          const unsigned short* __restrict__ Bt,
                          const float* __restrict__ bias,
                          const float* __restrict__ Cin,
                          float* __restrict__ Hout,
                          float* __restrict__ Cout) {
  __shared__ __align__(16) char smem[16384];   // As 8K | Bs 8K ; epilogue Gs 16K

  int t = threadIdx.x;
  int l = t & 63;
  int wave = t >> 6;
  int lane16 = l & 15;
  int kg = l >> 4;
  int wr = wave >> 1, wc = wave & 1;

  int bid = blockIdx.x;                 // 2048 blocks
  int swz = (bid & 7) * 256 + (bid >> 3);   // bijective XCD swizzle (2048%8==0)
  int tile_m = swz >> 5;                // 64 M-tiles
  int tile_n = swz & 31;                // 32 N-tiles
  int brow = tile_m * BM;
  int bcol = tile_n * BN;

  // staging: thread t loads 16B; rows (t>>2) and (t>>2)+64; LDS linear = t*16
  int srow = t >> 2;
  int sseg = (t & 3) * 8;
  const unsigned short* ga0 = A  + (size_t)(brow + srow)      * KDIM + sseg;
  const unsigned short* ga1 = A  + (size_t)(brow + srow + 64) * KDIM + sseg;
  const unsigned short* gb0 = Bt + (size_t)(bcol + srow)      * KDIM + sseg;
  const unsigned short* gb1 = Bt + (size_t)(bcol + srow + 64) * KDIM + sseg;
  char* lA0 = smem         + t * 16;
  char* lA1 = smem + 4096  + t * 16;
  char* lB0 = smem + 8192  + t * 16;
  char* lB1 = smem + 12288 + t * 16;

  f32x4 acc[4][4];
#pragma unroll
  for (int m = 0; m < 4; m++)
#pragma unroll
    for (int n = 0; n < 4; n++) acc[m][n] = (f32x4){0.f, 0.f, 0.f, 0.f};

  // fragment LDS byte offsets (row-major [128][32] bf16 = 64B rows)
  int aoff[4], boff[4];
#pragma unroll
  for (int m = 0; m < 4; m++)
    aoff[m] = (wr * 64 + m * 16 + lane16) * 64 + kg * 16;
#pragma unroll
  for (int n = 0; n < 4; n++)
    boff[n] = 8192 + (wc * 64 + n * 16 + lane16) * 64 + kg * 16;

  for (int kt = 0; kt < KDIM; kt += BK) {
    gload_lds16(ga0 + kt, lA0);
    gload_lds16(ga1 + kt, lA1);
    gload_lds16(gb0 + kt, lB0);
    gload_lds16(gb1 + kt, lB1);
    __syncthreads();
    bf16x8 af[4], bfr[4];
#pragma unroll
    for (int n = 0; n < 4; n++)
      bfr[n] = *reinterpret_cast<const bf16x8*>(smem + boff[n]);
#pragma unroll
    for (int m = 0; m < 4; m++)
      af[m] = *reinterpret_cast<const bf16x8*>(smem + aoff[m]);
#pragma unroll
    for (int m = 0; m < 4; m++)
#pragma unroll
      for (int n = 0; n < 4; n++)
        acc[m][n] = __builtin_amdgcn_mfma_f32_16x16x32_bf16(af[m], bfr[n],
                                                            acc[m][n], 0, 0, 0);
    __syncthreads();
  }

  // bias (function of column only)
  float bv[4];
#pragma unroll
  for (int n = 0; n < 4; n++)
    bv[n] = bias[bcol + wc * 64 + n * 16 + lane16];

  float* Gs = reinterpret_cast<float*>(smem);   // [32][128] per m-chunk

  // FULLY unrolled m-loop: every acc[m][n][r] index is compile-time constant
  // (runtime-indexed ext_vector arrays go to scratch -> 8 GB spill traffic, R1)
#pragma unroll
  for (int m = 0; m < 4; m++) {
    if (m) __syncthreads();
    // C/D layout: col = lane&15, row = (lane>>4)*4 + reg  [verified m89/m91]
#pragma unroll
    for (int n = 0; n < 4; n++)
#pragma unroll
      for (int r = 0; r < 4; r++)
        Gs[(wr * 16 + kg * 4 + r) * 128 + wc * 64 + n * 16 + lane16] =
            acc[m][n][r] + bv[n];
    __syncthreads();
#pragma unroll
    for (int q = 0; q < 4; q++) {
      int item = t + q * 256;            // 32 rows x 32 units
      int s = item >> 5;
      int u = item & 31;
      float4 g4 = *reinterpret_cast<const float4*>(&Gs[s * 128 + u * 4]);
      int grow = brow + (s >> 4) * 64 + m * 16 + (s & 15);
      int gu = (bcol >> 2) + u;
      float Ig = sigm(g4.x);
      float Fg = sigm(g4.y);
      float Gg = tanh_fast(g4.z);
      float Og = sigm(g4.w);
      size_t idx = (size_t)grow * H_DIM + gu;
      float cv = Cin[idx];
      float cn = Fg * cv + Ig * Gg;
      float hn = Og * tanh_fast(cn);
      Hout[idx] = hn;
      Cout[idx] = cn;
    }
  }
}

extern "C" void kernel_launch(void* const* d_in, const int* in_sizes, int n_in,
                              void* d_out, int out_size, void* d_ws, size_t ws_size,
                              hipStream_t stream) {
  const float* x  = (const float*)d_in[0];
  const float* h  = (const float*)d_in[1];
  const float* c  = (const float*)d_in[2];
  const float* Wi = (const float*)d_in[3];
  const float* bi = (const float*)d_in[4];
  const float* Wh = (const float*)d_in[5];
  const float* bh = (const float*)d_in[6];

  float* out  = (float*)d_out;
  float* Hout = out;
  float* Cout = out + (size_t)BATCH * H_DIM;

  // workspace layout: A bf16 (32 MiB) | Bt bf16 (16 MiB) | bias f32 (16 KiB)
  unsigned short* Abf = (unsigned short*)d_ws;
  unsigned short* Btb = (unsigned short*)((char*)d_ws + 33554432);
  float*          bsf = (float*)((char*)d_ws + 50331648);

  conv_a<<<2048, 256, 0, stream>>>(x, h, Abf);
  conv_b<<<dim3(64, 128), dim3(32, 8), 0, stream>>>(Wi, Wh, Btb);
  conv_bias<<<16, 256, 0, stream>>>(bi, bh, bsf);
  lstm_gemm<<<2048, 256, 0, stream>>>(Abf, Btb, bsf, c, Hout, Cout);
}

// Round 3
// 163.822 us; speedup vs baseline: 9.0593x; 1.3991x over previous
//
#include <hip/hip_runtime.h>
#include <stdint.h>

#define IN_DIM 1024
#define H_DIM  1024
#define BATCH  8192
#define KDIM   2048   // IN + H
#define NDIM   4096   // 4*H
#define BM     256
#define BN     256
#define BK     64
#define NT     (KDIM / BK)   // 32 K-tiles

typedef __bf16 bf16x8 __attribute__((ext_vector_type(8)));
typedef float  f32x4  __attribute__((ext_vector_type(4)));
typedef unsigned int u32;

static __device__ __forceinline__ unsigned short f2bf(float f) {
  u32 u = __builtin_bit_cast(u32, f);
  u += 0x7FFFu + ((u >> 16) & 1u);   // round-to-nearest-even
  return (unsigned short)(u >> 16);
}

static __device__ __forceinline__ float sigm(float x) {
  return 1.0f / (1.0f + __expf(-x));
}
static __device__ __forceinline__ float tanh_fast(float x) {
  float e = __expf(-2.0f * fabsf(x));     // in (0,1], no overflow
  float t = (1.0f - e) / (1.0f + e);
  return copysignf(t, x);
}

// ---------------- prep 1: A = [x | h] -> bf16 [BATCH][KDIM] ----------------
__global__ void conv_a(const float* __restrict__ x, const float* __restrict__ h,
                       unsigned short* __restrict__ A) {
  const int total = BATCH * KDIM / 4;
  for (int i = blockIdx.x * blockDim.x + threadIdx.x; i < total;
       i += gridDim.x * blockDim.x) {
    int b = i >> 9;              // 512 quads per row
    int k = (i & 511) << 2;
    const float* src = (k < IN_DIM) ? (x + (size_t)b * IN_DIM + k)
                                    : (h + (size_t)b * H_DIM + (k - IN_DIM));
    float4 v = *reinterpret_cast<const float4*>(src);
    ushort4 o;
    o.x = f2bf(v.x); o.y = f2bf(v.y); o.z = f2bf(v.z); o.w = f2bf(v.w);
    *reinterpret_cast<ushort4*>(A + (size_t)b * KDIM + k) = o;
  }
}

// ---- prep 2: Bt[j][k] = W[k][c(j)], bf16, gate-interleaved cols j=4u+g ----
__global__ void conv_b(const float* __restrict__ Wi, const float* __restrict__ Wh,
                       unsigned short* __restrict__ Bt) {
  __shared__ float tile[32][33];
  int k0 = blockIdx.x * 32;            // 0..2047 (k of combined [Wi;Wh])
  int c0 = blockIdx.y * 32;            // 0..4095 (orig col)
  int tx = threadIdx.x;                // 0..31
  int ty = threadIdx.y;                // 0..7
  const float* src = (k0 < IN_DIM) ? (Wi + (size_t)k0 * NDIM)
                                   : (Wh + (size_t)(k0 - IN_DIM) * NDIM);
  for (int i = 0; i < 4; i++) {
    int r = ty + 8 * i;
    tile[r][tx] = src[(size_t)r * NDIM + c0 + tx];
  }
  __syncthreads();
  int g = c0 >> 10;                    // gate index (tile doesn't straddle)
  int ubase = c0 & 1023;
  for (int i = 0; i < 4; i++) {
    int cc = ty + 8 * i;
    int j = 4 * (ubase + cc) + g;      // interleaved output row
    Bt[(size_t)j * KDIM + k0 + tx] = f2bf(tile[tx][cc]);
  }
}

// ---------------- prep 3: bias[j] = bi[c(j)] + bh[c(j)] ----------------
__global__ void conv_bias(const float* __restrict__ bi, const float* __restrict__ bh,
                          float* __restrict__ bias) {
  int j = blockIdx.x * blockDim.x + threadIdx.x;
  if (j < NDIM) {
    int c = ((j & 3) << 10) + (j >> 2);
    bias[j] = bi[c] + bh[c];
  }
}

// ---------------- 256x256 8-phase GEMM + fused LSTM epilogue ----------------
static __device__ __forceinline__ void gload_lds16(const void* g, void* l) {
  __builtin_amdgcn_global_load_lds(
      (const __attribute__((address_space(1))) u32*)g,
      (__attribute__((address_space(3))) u32*)l, 16, 0, 0);
}

#define MFMA __builtin_amdgcn_mfma_f32_16x16x32_bf16

__launch_bounds__(512, 2)
__global__ void lstm_gemm(const unsigned short* __restrict__ A,
                          const unsigned short* __restrict__ Bt,
                          const float* __restrict__ bias,
                          const float* __restrict__ Cin,
                          float* __restrict__ Hout,
                          float* __restrict__ Cout) {
  // LDS: A [2 buf][2 half][128 rows][128B] = 64K | B same = 64K  (128 KiB)
  __shared__ __align__(16) char smem[131072];

  const int t  = threadIdx.x;
  const int l  = t & 63;
  const int w  = t >> 6;           // wave 0-7
  const int lane16 = l & 15;
  const int kg = l >> 4;           // 0-3
  const int wr = w >> 2;           // 0-1  (M)
  const int wc = w & 3;            // 0-3  (N)

  int bid = blockIdx.x;            // 512 blocks (32 M-tiles x 16 N-tiles)
  int swz = (bid & 7) * 64 + (bid >> 3);   // bijective XCD swizzle (512%8==0)
  int brow = (swz >> 4) * BM;
  int bcol = (swz & 15) * BN;

  // ---- staging addresses (q=0,1): slot=(w*2+q)*64+l; linear LDS dest,
  //      pre-swizzled global source chunk c = (slot&7) ^ ((slot>>3)&7) ----
  int slot0 = (w * 2 + 0) * 64 + l, slot1 = (w * 2 + 1) * 64 + l;
  int rih0 = slot0 >> 3, rih1 = slot1 >> 3;
  int c0 = (slot0 & 7) ^ (rih0 & 7), c1 = (slot1 & 7) ^ (rih1 & 7);
  const unsigned short* pA0 = A + (size_t)(brow + (rih0 >> 6) * 128 + (rih0 & 63)) * KDIM + c0 * 8;
  const unsigned short* pA1 = A + (size_t)(brow + (rih1 >> 6) * 128 + (rih1 & 63)) * KDIM + c1 * 8;
  const unsigned short* pB0 = Bt + (size_t)(bcol + (rih0 >> 5) * 64 + (rih0 & 31)) * KDIM + c0 * 8;
  const unsigned short* pB1 = Bt + (size_t)(bcol + (rih1 >> 5) * 64 + (rih1 & 31)) * KDIM + c1 * 8;
  char* lds0 = smem + w * 2048 + l * 16;          // q=0 lane dest
  char* lds1 = smem + w * 2048 + 1024 + l * 16;   // q=1 lane dest

  auto STAGE_A = [&](int h, int tt, int bb) {
    gload_lds16(pA0 + (size_t)h * 131072 + tt * BK, lds0 + bb + h * 16384);
    gload_lds16(pA1 + (size_t)h * 131072 + tt * BK, lds1 + bb + h * 16384);
  };
  auto STAGE_B = [&](int h, int tt, int bb) {
    gload_lds16(pB0 + (size_t)h * 65536 + tt * BK, lds0 + 65536 + bb + h * 16384);
    gload_lds16(pB1 + (size_t)h * 65536 + tt * BK, lds1 + 65536 + bb + h * 16384);
  };

  // ---- fragment read offsets (XOR-swizzled: chunk ^= (row&7)<<4) ----
  int msk = (lane16 & 7) << 4;
  int chs0 = (kg * 16) ^ msk;          // k-step 0
  int chs1 = (64 + kg * 16) ^ msk;     // k-step 1
  int arow[4], browf[4];
#pragma unroll
  for (int mm = 0; mm < 4; mm++)
    arow[mm] = (wr * 64 + mm * 16 + lane16) * 128;
#pragma unroll
  for (int nn = 0; nn < 4; nn++)
    browf[nn] = 65536 + (nn >> 1) * 16384 + (wc * 32 + (nn & 1) * 16 + lane16) * 128;

  f32x4 acc[8][4];
#pragma unroll
  for (int m = 0; m < 8; m++)
#pragma unroll
    for (int n = 0; n < 4; n++) acc[m][n] = (f32x4){0.f, 0.f, 0.f, 0.f};

  // ---- prologue: tile0 (4 halves) + tile1 (3 halves); drain to 6 ----
  STAGE_A(0, 0, 0);     STAGE_B(0, 0, 0);
  STAGE_A(1, 0, 0);     STAGE_B(1, 0, 0);
  STAGE_A(0, 1, 32768); STAGE_B(0, 1, 32768); STAGE_A(1, 1, 32768);
  asm volatile("s_waitcnt vmcnt(6)" ::: "memory");
  __builtin_amdgcn_s_barrier();

  bf16x8 afr[4][2], bfr[4][2];

  for (int tk = 0; tk < NT; ++tk) {
    const int bb  = (tk & 1) * 32768;
    const int bbn = bb ^ 32768;
    const int tB = (tk + 1 < NT) ? tk + 1 : NT - 1;   // clamp keeps vmcnt exact;
    const int tA = (tk + 2 < NT) ? tk + 2 : NT - 1;   // redundant stages rewrite identical bytes

    // ---- phase 1: read A m0-3 + B n0-1 (12 reads); stage B1(t+1); Q1 ----
#pragma unroll
    for (int mm = 0; mm < 4; mm++) {
      afr[mm][0] = *(const bf16x8*)(smem + bb + arow[mm] + chs0);
      afr[mm][1] = *(const bf16x8*)(smem + bb + arow[mm] + chs1);
    }
#pragma unroll
    for (int nn = 0; nn < 2; nn++) {
      bfr[nn][0] = *(const bf16x8*)(smem + bb + browf[nn] + chs0);
      bfr[nn][1] = *(const bf16x8*)(smem + bb + browf[nn] + chs1);
    }
    STAGE_B(1, tB, bbn);
    __builtin_amdgcn_s_barrier();
    asm volatile("s_waitcnt lgkmcnt(0)" ::: "memory");
    __builtin_amdgcn_s_setprio(1);
#pragma unroll
    for (int mm = 0; mm < 4; mm++)
#pragma unroll
      for (int nn = 0; nn < 2; nn++) {
        acc[mm][nn] = MFMA(afr[mm][0], bfr[nn][0], acc[mm][nn], 0, 0, 0);
        acc[mm][nn] = MFMA(afr[mm][1], bfr[nn][1], acc[mm][nn], 0, 0, 0);
      }
    __builtin_amdgcn_s_setprio(0);
    __builtin_amdgcn_s_barrier();

    // ---- phase 2: read B n2-3 (4 reads); stage A0(t+2); Q2 ----
#pragma unroll
    for (int nn = 2; nn < 4; nn++) {
      bfr[nn][0] = *(const bf16x8*)(smem + bb + browf[nn] + chs0);
      bfr[nn][1] = *(const bf16x8*)(smem + bb + browf[nn] + chs1);
    }
    STAGE_A(0, tA, bb);
    __builtin_amdgcn_s_barrier();
    asm volatile("s_waitcnt lgkmcnt(0)" ::: "memory");
    __builtin_amdgcn_s_setprio(1);
#pragma unroll
    for (int mm = 0; mm < 4; mm++)
#pragma unroll
      for (int nn = 2; nn < 4; nn++) {
        acc[mm][nn] = MFMA(afr[mm][0], bfr[nn][0], acc[mm][nn], 0, 0, 0);
        acc[mm][nn] = MFMA(afr[mm][1], bfr[nn][1], acc[mm][nn], 0, 0, 0);
      }
    __builtin_amdgcn_s_setprio(0);
    __builtin_amdgcn_s_barrier();

    // ---- phase 3: read A m4-7 (8 reads); stage B0(t+2); Q3 ----
#pragma unroll
    for (int mm = 0; mm < 4; mm++) {
      afr[mm][0] = *(const bf16x8*)(smem + bb + 16384 + arow[mm] + chs0);
      afr[mm][1] = *(const bf16x8*)(smem + bb + 16384 + arow[mm] + chs1);
    }
    STAGE_B(0, tA, bb);
    __builtin_amdgcn_s_barrier();
    asm volatile("s_waitcnt lgkmcnt(0)" ::: "memory");
    __builtin_amdgcn_s_setprio(1);
#pragma unroll
    for (int mm = 0; mm < 4; mm++)
#pragma unroll
      for (int nn = 0; nn < 2; nn++) {
        acc[4 + mm][nn] = MFMA(afr[mm][0], bfr[nn][0], acc[4 + mm][nn], 0, 0, 0);
        acc[4 + mm][nn] = MFMA(afr[mm][1], bfr[nn][1], acc[4 + mm][nn], 0, 0, 0);
      }
    __builtin_amdgcn_s_setprio(0);
    __builtin_amdgcn_s_barrier();

    // ---- phase 4: stage A1(t+2); vmcnt(6) -> tile t+1 fully landed; Q4 ----
    STAGE_A(1, tA, bb);
    asm volatile("s_waitcnt vmcnt(6)" ::: "memory");
    __builtin_amdgcn_s_barrier();
    __builtin_amdgcn_s_setprio(1);
#pragma unroll
    for (int mm = 0; mm < 4; mm++)
#pragma unroll
      for (int nn = 2; nn < 4; nn++) {
        acc[4 + mm][nn] = MFMA(afr[mm][0], bfr[nn][0], acc[4 + mm][nn], 0, 0, 0);
        acc[4 + mm][nn] = MFMA(afr[mm][1], bfr[nn][1], acc[4 + mm][nn], 0, 0, 0);
      }
    __builtin_amdgcn_s_setprio(0);
    __builtin_amdgcn_s_barrier();
  }

  // ---- epilogue: drain stages, then wave-local LDS transpose + gates ----
  asm volatile("s_waitcnt vmcnt(0)" ::: "memory");
  __builtin_amdgcn_s_barrier();

  float bv[4];
#pragma unroll
  for (int nn = 0; nn < 4; nn++)
    bv[nn] = bias[bcol + wc * 64 + nn * 16 + lane16];

  float* Gep = (float*)(smem + (size_t)w * 4352);   // 16 rows x 68 f32 per wave

#pragma unroll
  for (int m = 0; m < 8; m++) {
    // C/D layout: col = lane&15, row = kg*4 + reg  [verified m89/m91]
#pragma unroll
    for (int nn = 0; nn < 4; nn++)
#pragma unroll
      for (int r = 0; r < 4; r++)
        Gep[(kg * 4 + r) * 68 + nn * 16 + lane16] = acc[m][nn][r] + bv[nn];
    asm volatile("s_waitcnt lgkmcnt(0)" ::: "memory");
#pragma unroll
    for (int p = 0; p < 4; p++) {
      int row = p * 4 + kg;
      const float4 g4 = *(const float4*)(Gep + row * 68 + lane16 * 4);
      int R = brow + wr * 128 + m * 16 + row;
      int U = (bcol >> 2) + wc * 16 + lane16;
      float Ig = sigm(g4.x);
      float Fg = sigm(g4.y);
      float Gg = tanh_fast(g4.z);
      float Og = sigm(g4.w);
      size_t idx = (size_t)R * H_DIM + U;
      float cv = Cin[idx];
      float cn = Fg * cv + Ig * Gg;
      Hout[idx] = Og * tanh_fast(cn);
      Cout[idx] = cn;
    }
    asm volatile("s_waitcnt lgkmcnt(0)" ::: "memory");
  }
}

extern "C" void kernel_launch(void* const* d_in, const int* in_sizes, int n_in,
                              void* d_out, int out_size, void* d_ws, size_t ws_size,
                              hipStream_t stream) {
  const float* x  = (const float*)d_in[0];
  const float* h  = (const float*)d_in[1];
  const float* c  = (const float*)d_in[2];
  const float* Wi = (const float*)d_in[3];
  const float* bi = (const float*)d_in[4];
  const float* Wh = (const float*)d_in[5];
  const float* bh = (const float*)d_in[6];

  float* out  = (float*)d_out;
  float* Hout = out;
  float* Cout = out + (size_t)BATCH * H_DIM;

  // workspace layout: A bf16 (32 MiB) | Bt bf16 (16 MiB) | bias f32 (16 KiB)
  unsigned short* Abf = (unsigned short*)d_ws;
  unsigned short* Btb = (unsigned short*)((char*)d_ws + 33554432);
  float*          bsf = (float*)((char*)d_ws + 50331648);

  conv_a<<<2048, 256, 0, stream>>>(x, h, Abf);
  conv_b<<<dim3(64, 128), dim3(32, 8), 0, stream>>>(Wi, Wh, Btb);
  conv_bias<<<16, 256, 0, stream>>>(bi, bh, bsf);
  lstm_gemm<<<512, 512, 0, stream>>>(Abf, Btb, bsf, c, Hout, Cout);
}

// Round 4
// 162.569 us; speedup vs baseline: 9.1291x; 1.0077x over previous
//
#include <hip/hip_runtime.h>
#include <stdint.h>

#define IN_DIM 1024
#define H_DIM  1024
#define BATCH  8192
#define KDIM   2048   // IN + H
#define NDIM   4096   // 4*H
#define BM     256
#define BN     256
#define BK     64
#define NT     (KDIM / BK)   // 32 K-tiles

typedef __bf16 bf16x8 __attribute__((ext_vector_type(8)));
typedef float  f32x4  __attribute__((ext_vector_type(4)));
typedef unsigned int u32;

static __device__ __forceinline__ unsigned short f2bf(float f) {
  u32 u = __builtin_bit_cast(u32, f);
  u += 0x7FFFu + ((u >> 16) & 1u);   // round-to-nearest-even
  return (unsigned short)(u >> 16);
}

static __device__ __forceinline__ float sigm(float x) {
  return 1.0f / (1.0f + __expf(-x));
}
static __device__ __forceinline__ float tanh_fast(float x) {
  float e = __expf(-2.0f * fabsf(x));     // in (0,1], no overflow
  float t = (1.0f - e) / (1.0f + e);
  return copysignf(t, x);
}

// ---------------- prep 1: A = [x | h] -> bf16 [BATCH][KDIM] ----------------
__global__ void conv_a(const float* __restrict__ x, const float* __restrict__ h,
                       unsigned short* __restrict__ A) {
  const int total = BATCH * KDIM / 4;
  for (int i = blockIdx.x * blockDim.x + threadIdx.x; i < total;
       i += gridDim.x * blockDim.x) {
    int b = i >> 9;              // 512 quads per row
    int k = (i & 511) << 2;
    const float* src = (k < IN_DIM) ? (x + (size_t)b * IN_DIM + k)
                                    : (h + (size_t)b * H_DIM + (k - IN_DIM));
    float4 v = *reinterpret_cast<const float4*>(src);
    ushort4 o;
    o.x = f2bf(v.x); o.y = f2bf(v.y); o.z = f2bf(v.z); o.w = f2bf(v.w);
    *reinterpret_cast<ushort4*>(A + (size_t)b * KDIM + k) = o;
  }
}

// ---- prep 2: Bt[j][k] = W[k][c(j)], bf16, gate-interleaved cols j=4u+g ----
__global__ void conv_b(const float* __restrict__ Wi, const float* __restrict__ Wh,
                       unsigned short* __restrict__ Bt) {
  __shared__ float tile[32][33];
  int k0 = blockIdx.x * 32;            // 0..2047 (k of combined [Wi;Wh])
  int c0 = blockIdx.y * 32;            // 0..4095 (orig col)
  int tx = threadIdx.x;                // 0..31
  int ty = threadIdx.y;                // 0..7
  const float* src = (k0 < IN_DIM) ? (Wi + (size_t)k0 * NDIM)
                                   : (Wh + (size_t)(k0 - IN_DIM) * NDIM);
  for (int i = 0; i < 4; i++) {
    int r = ty + 8 * i;
    tile[r][tx] = src[(size_t)r * NDIM + c0 + tx];
  }
  __syncthreads();
  int g = c0 >> 10;                    // gate index (tile doesn't straddle)
  int ubase = c0 & 1023;
  for (int i = 0; i < 4; i++) {
    int cc = ty + 8 * i;
    int j = 4 * (ubase + cc) + g;      // interleaved output row
    Bt[(size_t)j * KDIM + k0 + tx] = f2bf(tile[tx][cc]);
  }
}

// ---------------- prep 3: bias[j] = bi[c(j)] + bh[c(j)] ----------------
__global__ void conv_bias(const float* __restrict__ bi, const float* __restrict__ bh,
                          float* __restrict__ bias) {
  int j = blockIdx.x * blockDim.x + threadIdx.x;
  if (j < NDIM) {
    int c = ((j & 3) << 10) + (j >> 2);
    bias[j] = bi[c] + bh[c];
  }
}

// ---------------- 256x256 8-phase GEMM + fused LSTM epilogue ----------------
static __device__ __forceinline__ void gload_lds16(const void* g, void* l) {
  __builtin_amdgcn_global_load_lds(
      (const __attribute__((address_space(1))) u32*)g,
      (__attribute__((address_space(3))) u32*)l, 16, 0, 0);
}

#define MFMA __builtin_amdgcn_mfma_f32_16x16x32_bf16

__launch_bounds__(512, 2)
__global__ void lstm_gemm(const unsigned short* __restrict__ A,
                          const unsigned short* __restrict__ Bt,
                          const float* __restrict__ bias,
                          const float* __restrict__ Cin,
                          float* __restrict__ Hout,
                          float* __restrict__ Cout) {
  // LDS: A [2 buf][2 half][128 rows][128B] = 64K | B same = 64K  (128 KiB)
  __shared__ __align__(16) char smem[131072];

  const int t  = threadIdx.x;
  const int l  = t & 63;
  const int w  = t >> 6;           // wave 0-7
  const int lane16 = l & 15;
  const int kg = l >> 4;           // 0-3
  const int wr = w >> 2;           // 0-1  (M)
  const int wc = w & 3;            // 0-3  (N)

  int bid = blockIdx.x;            // 512 blocks (32 M-tiles x 16 N-tiles)
  int swz = (bid & 7) * 64 + (bid >> 3);   // bijective XCD swizzle (512%8==0)
  int brow = (swz >> 4) * BM;
  int bcol = (swz & 15) * BN;

  // ---- staging: slot=(w*2+q)*64+l, LDS linear slot*16; global source chunk
  //      pre-swizzled c = (slot&7) ^ (row&7)  (read side XORs the same) ----
  int slot0 = w * 128 + l, slot1 = slot0 + 64;
  int rih0 = slot0 >> 3, rih1 = slot1 >> 3;
  int c0 = (slot0 & 7) ^ (rih0 & 7), c1 = (slot1 & 7) ^ (rih1 & 7);

  // 8 rolling global pointers (A/B x half0/1 x slot q0/q1), bumped 64 elem/K-tile
  const unsigned short* a0q0 = A + (size_t)(brow + (rih0 >> 6) * 128 + (rih0 & 63)) * KDIM + c0 * 8;
  const unsigned short* a0q1 = A + (size_t)(brow + (rih1 >> 6) * 128 + (rih1 & 63)) * KDIM + c1 * 8;
  const unsigned short* a1q0 = a0q0 + 131072;   // +64 rows
  const unsigned short* a1q1 = a0q1 + 131072;
  const unsigned short* b0q0 = Bt + (size_t)(bcol + (rih0 >> 5) * 64 + (rih0 & 31)) * KDIM + c0 * 8;
  const unsigned short* b0q1 = Bt + (size_t)(bcol + (rih1 >> 5) * 64 + (rih1 & 31)) * KDIM + c1 * 8;
  const unsigned short* b1q0 = b0q0 + 65536;    // +32 rows
  const unsigned short* b1q1 = b0q1 + 65536;

#define GL(gp, loff) gload_lds16((gp), smem + (loff) + w * 2048 + l * 16)

  // ---- per-lane ds_read base addresses; everything else folds to offset: ----
  const int msk = (lane16 & 7) << 4;
  char* vA0 = smem + wr * 8192 + lane16 * 128 + ((kg * 16) ^ msk);
  char* vA1 = smem + wr * 8192 + lane16 * 128 + ((64 + kg * 16) ^ msk);
  char* vB0 = smem + 65536 + wc * 4096 + lane16 * 128 + ((kg * 16) ^ msk);
  char* vB1 = smem + 65536 + wc * 4096 + lane16 * 128 + ((64 + kg * 16) ^ msk);

  f32x4 acc[8][4];
#pragma unroll
  for (int m = 0; m < 8; m++)
#pragma unroll
    for (int n = 0; n < 4; n++) acc[m][n] = (f32x4){0.f, 0.f, 0.f, 0.f};

  // ---- prologue: tile0 (4 halves) -> buf0, tile1 (3 halves) -> buf1 ----
  GL(a0q0, 0);                 GL(a0q1, 1024);
  GL(b0q0, 65536);             GL(b0q1, 65536 + 1024);
  GL(a1q0, 16384);             GL(a1q1, 16384 + 1024);
  GL(b1q0, 65536 + 16384);     GL(b1q1, 65536 + 16384 + 1024);
  GL(a0q0 + 64, 32768);        GL(a0q1 + 64, 32768 + 1024);
  GL(b0q0 + 64, 65536 + 32768);GL(b0q1 + 64, 65536 + 32768 + 1024);
  GL(a1q0 + 64, 32768 + 16384);GL(a1q1 + 64, 32768 + 16384 + 1024);
  asm volatile("s_waitcnt vmcnt(6)" ::: "memory");
  __builtin_amdgcn_s_barrier();
  // roll: A-halves & B0 -> tile2, B1 -> tile1
  a0q0 += 128; a0q1 += 128; a1q0 += 128; a1q1 += 128;
  b0q0 += 128; b0q1 += 128; b1q0 += 64;  b1q1 += 64;

  bf16x8 afr[4][2], bfr[4][2];

#define BODY(P)                                                              \
  {                                                                          \
    /* phase 1: read A half0 (m0-3) + B half0 (n0-1); stage B1(t+1)->buf^1 */\
    _Pragma("unroll") for (int mm = 0; mm < 4; mm++) {                       \
      afr[mm][0] = *(const bf16x8*)(vA0 + (P)*32768 + mm*2048);              \
      afr[mm][1] = *(const bf16x8*)(vA1 + (P)*32768 + mm*2048);              \
    }                                                                        \
    _Pragma("unroll") for (int nn = 0; nn < 2; nn++) {                       \
      bfr[nn][0] = *(const bf16x8*)(vB0 + (P)*32768 + nn*2048);              \
      bfr[nn][1] = *(const bf16x8*)(vB1 + (P)*32768 + nn*2048);              \
    }                                                                        \
    GL(b1q0, 65536 + ((P)^1)*32768 + 16384);                                 \
    GL(b1q1, 65536 + ((P)^1)*32768 + 16384 + 1024);                          \
    __builtin_amdgcn_s_barrier();                                            \
    asm volatile("s_waitcnt lgkmcnt(0)" ::: "memory");                       \
    __builtin_amdgcn_s_setprio(1);                                           \
    _Pragma("unroll") for (int mm = 0; mm < 4; mm++)                         \
      _Pragma("unroll") for (int nn = 0; nn < 2; nn++) {                     \
        acc[mm][nn] = MFMA(afr[mm][0], bfr[nn][0], acc[mm][nn], 0, 0, 0);    \
        acc[mm][nn] = MFMA(afr[mm][1], bfr[nn][1], acc[mm][nn], 0, 0, 0);    \
      }                                                                      \
    __builtin_amdgcn_s_setprio(0);                                           \
    __builtin_amdgcn_s_barrier();                                            \
    /* phase 2: read B half1 (n2-3); stage A0(t+2)->buf P */                 \
    _Pragma("unroll") for (int nn = 2; nn < 4; nn++) {                       \
      bfr[nn][0] = *(const bf16x8*)(vB0 + (P)*32768 + 16384 + (nn-2)*2048);  \
      bfr[nn][1] = *(const bf16x8*)(vB1 + (P)*32768 + 16384 + (nn-2)*2048);  \
    }                                                                        \
    GL(a0q0, (P)*32768);                                                     \
    GL(a0q1, (P)*32768 + 1024);                                              \
    __builtin_amdgcn_s_barrier();                                            \
    asm volatile("s_waitcnt lgkmcnt(0)" ::: "memory");                       \
    __builtin_amdgcn_s_setprio(1);                                           \
    _Pragma("unroll") for (int mm = 0; mm < 4; mm++)                         \
      _Pragma("unroll") for (int nn = 2; nn < 4; nn++) {                     \
        acc[mm][nn] = MFMA(afr[mm][0], bfr[nn][0], acc[mm][nn], 0, 0, 0);    \
        acc[mm][nn] = MFMA(afr[mm][1], bfr[nn][1], acc[mm][nn], 0, 0, 0);    \
      }                                                                      \
    __builtin_amdgcn_s_setprio(0);                                           \
    __builtin_amdgcn_s_barrier();                                            \
    /* phase 3: read A half1 (m4-7); stage B0(t+2)->buf P */                 \
    _Pragma("unroll") for (int mm = 0; mm < 4; mm++) {                       \
      afr[mm][0] = *(const bf16x8*)(vA0 + (P)*32768 + 16384 + mm*2048);      \
      afr[mm][1] = *(const bf16x8*)(vA1 + (P)*32768 + 16384 + mm*2048);      \
    }                                                                        \
    GL(b0q0, 65536 + (P)*32768);                                             \
    GL(b0q1, 65536 + (P)*32768 + 1024);                                      \
    __builtin_amdgcn_s_barrier();                                            \
    asm volatile("s_waitcnt lgkmcnt(0)" ::: "memory");                       \
    __builtin_amdgcn_s_setprio(1);                                           \
    _Pragma("unroll") for (int mm = 0; mm < 4; mm++)                         \
      _Pragma("unroll") for (int nn = 0; nn < 2; nn++) {                     \
        acc[4+mm][nn] = MFMA(afr[mm][0], bfr[nn][0], acc[4+mm][nn], 0, 0, 0);\
        acc[4+mm][nn] = MFMA(afr[mm][1], bfr[nn][1], acc[4+mm][nn], 0, 0, 0);\
      }                                                                      \
    __builtin_amdgcn_s_setprio(0);                                           \
    __builtin_amdgcn_s_barrier();                                            \
    /* phase 4: stage A1(t+2)->buf P; vmcnt(6) -> tile t+1 fully landed */   \
    GL(a1q0, (P)*32768 + 16384);                                             \
    GL(a1q1, (P)*32768 + 16384 + 1024);                                      \
    asm volatile("s_waitcnt vmcnt(6)" ::: "memory");                         \
    __builtin_amdgcn_s_barrier();                                            \
    __builtin_amdgcn_s_setprio(1);                                           \
    _Pragma("unroll") for (int mm = 0; mm < 4; mm++)                         \
      _Pragma("unroll") for (int nn = 2; nn < 4; nn++) {                     \
        acc[4+mm][nn] = MFMA(afr[mm][0], bfr[nn][0], acc[4+mm][nn], 0, 0, 0);\
        acc[4+mm][nn] = MFMA(afr[mm][1], bfr[nn][1], acc[4+mm][nn], 0, 0, 0);\
      }                                                                      \
    __builtin_amdgcn_s_setprio(0);                                           \
    __builtin_amdgcn_s_barrier();                                            \
    a0q0 += 64; a0q1 += 64; a1q0 += 64; a1q1 += 64;                          \
    b0q0 += 64; b0q1 += 64; b1q0 += 64; b1q1 += 64;                          \
  }

  for (int it = 0; it < NT / 2; ++it) {
    BODY(0)
    BODY(1)
  }
#undef BODY
#undef GL

  // ---- epilogue: drain stages, then wave-local LDS transpose + gates ----
  asm volatile("s_waitcnt vmcnt(0)" ::: "memory");
  __builtin_amdgcn_s_barrier();

  float bv[4];
#pragma unroll
  for (int nn = 0; nn < 4; nn++)
    bv[nn] = bias[bcol + wc * 64 + nn * 16 + lane16];

  float* Gep = (float*)(smem + (size_t)w * 4352);   // 16 rows x 68 f32 per wave

#pragma unroll
  for (int m = 0; m < 8; m++) {
    // C/D layout: col = lane&15, row = kg*4 + reg  [verified m89/m91]
#pragma unroll
    for (int nn = 0; nn < 4; nn++)
#pragma unroll
      for (int r = 0; r < 4; r++)
        Gep[(kg * 4 + r) * 68 + nn * 16 + lane16] = acc[m][nn][r] + bv[nn];
    asm volatile("s_waitcnt lgkmcnt(0)" ::: "memory");
#pragma unroll
    for (int p = 0; p < 4; p++) {
      int row = p * 4 + kg;
      const float4 g4 = *(const float4*)(Gep + row * 68 + lane16 * 4);
      int R = brow + wr * 128 + m * 16 + row;
      int U = (bcol >> 2) + wc * 16 + lane16;
      float Ig = sigm(g4.x);
      float Fg = sigm(g4.y);
      float Gg = tanh_fast(g4.z);
      float Og = sigm(g4.w);
      size_t idx = (size_t)R * H_DIM + U;
      float cv = Cin[idx];
      float cn = Fg * cv + Ig * Gg;
      Hout[idx] = Og * tanh_fast(cn);
      Cout[idx] = cn;
    }
    asm volatile("s_waitcnt lgkmcnt(0)" ::: "memory");
  }
}

extern "C" void kernel_launch(void* const* d_in, const int* in_sizes, int n_in,
                              void* d_out, int out_size, void* d_ws, size_t ws_size,
                              hipStream_t stream) {
  const float* x  = (const float*)d_in[0];
  const float* h  = (const float*)d_in[1];
  const float* c  = (const float*)d_in[2];
  const float* Wi = (const float*)d_in[3];
  const float* bi = (const float*)d_in[4];
  const float* Wh = (const float*)d_in[5];
  const float* bh = (const float*)d_in[6];

  float* out  = (float*)d_out;
  float* Hout = out;
  float* Cout = out + (size_t)BATCH * H_DIM;

  // workspace layout: A bf16 (32 MiB) | Bt bf16 (16 MiB) | bias f32 (16 KiB)
  unsigned short* Abf = (unsigned short*)d_ws;
  unsigned short* Btb = (unsigned short*)((char*)d_ws + 33554432);
  float*          bsf = (float*)((char*)d_ws + 50331648);

  conv_a<<<2048, 256, 0, stream>>>(x, h, Abf);
  conv_b<<<dim3(64, 128), dim3(32, 8), 0, stream>>>(Wi, Wh, Btb);
  conv_bias<<<16, 256, 0, stream>>>(bi, bh, bsf);
  lstm_gemm<<<512, 512, 0, stream>>>(Abf, Btb, bsf, c, Hout, Cout);
}